// Round 2
// baseline (269.345 us; speedup 1.0000x reference)
//
#include <hip/hip_runtime.h>

#define B_    4
#define N_OBJ 24
#define C_    256
#define H_    100
#define W_    100
#define HW_   (H_ * W_)
#define OUT_  7
#define P_    276              // N*(N-1)/2
#define SCALE_ 0.25f
#define CHW_OUT (C_ * OUT_ * OUT_)   // 12544 floats per roi-slot chunk

typedef float f4_t __attribute__((ext_vector_type(4)));

// ---------------------------------------------------------------- transpose
// feat [B,C,H,W] -> featT [B,H*W,C]   (near-roofline already, unchanged)
__global__ __launch_bounds__(256) void transpose_kernel(
        const float* __restrict__ feat, float* __restrict__ featT) {
    __shared__ float tile[64][65];
    const int b   = blockIdx.z;
    const int c0  = blockIdx.y * 64;
    const int px0 = blockIdx.x * 64;
    const int t   = threadIdx.x;
    const int cl  = t >> 6;   // 0..3
    const int px  = t & 63;
#pragma unroll
    for (int k = 0; k < 16; ++k) {
        const int c_loc = cl + k * 4;
        const int gpx   = px0 + px;
        tile[c_loc][px] = (gpx < HW_)
            ? feat[((size_t)b * C_ + c0 + c_loc) * HW_ + gpx] : 0.0f;
    }
    __syncthreads();
    const int c2 = t & 63;
    const int pl = t >> 6;
#pragma unroll
    for (int k = 0; k < 16; ++k) {
        const int px_l = pl + k * 4;
        const int gpx  = px0 + px_l;
        if (gpx < HW_)
            featT[((size_t)b * HW_ + gpx) * C_ + c0 + c2] = tile[c2][px_l];
    }
}

// ---------------------------------------------------------------- pooling core
// Lane covers 4 channels (float4), wave covers a bin. Exact row/col dedup:
// bilinear weights are a rank-1 outer product, so duplicate corner rows/cols
// (small bins, edge clamps) merge by summing weights; zero-weight loads
// skipped via wave-uniform branches. Result lands in lds[c*49+s].
__device__ __forceinline__ void pool_to_lds(
        const f4_t* __restrict__ fbase, float x1, float y1, float x2, float y2,
        float* __restrict__ lds, int lane, int wv) {
    x1 *= SCALE_; y1 *= SCALE_; x2 *= SCALE_; y2 *= SCALE_;
    const float bin_w = fmaxf(x2 - x1, 1.0f) * (1.0f / OUT_);
    const float bin_h = fmaxf(y2 - y1, 1.0f) * (1.0f / OUT_);

    for (int s = wv; s < OUT_ * OUT_; s += 4) {
        const int ph = s / OUT_, pw = s - ph * OUT_;

        int ri_[4]; float rw_[4];
        {
            const float Ya = y1 + ((float)ph + 0.25f) * bin_h;
            const float Yb = y1 + ((float)ph + 0.75f) * bin_h;
            const float va = (Ya > -1.0f && Ya < (float)H_) ? 1.0f : 0.0f;
            const float vb = (Yb > -1.0f && Yb < (float)H_) ? 1.0f : 0.0f;
            const float Yca = fminf(fmaxf(Ya, 0.0f), (float)(H_ - 1));
            const float Ycb = fminf(fmaxf(Yb, 0.0f), (float)(H_ - 1));
            const int y0a = (int)floorf(Yca);
            const int y0b = (int)floorf(Ycb);
            const float lya = Yca - (float)y0a;
            const float lyb = Ycb - (float)y0b;
            ri_[0] = y0a; ri_[1] = min(y0a + 1, H_ - 1);
            ri_[2] = y0b; ri_[3] = min(y0b + 1, H_ - 1);
            rw_[0] = va * (1.0f - lya); rw_[1] = va * lya;
            rw_[2] = vb * (1.0f - lyb); rw_[3] = vb * lyb;
            if (ri_[1] == ri_[0]) { rw_[0] += rw_[1]; rw_[1] = 0.0f; }
            if (ri_[3] == ri_[2]) { rw_[2] += rw_[3]; rw_[3] = 0.0f; }
            if (ri_[2] == ri_[0]) {
                rw_[0] += rw_[2]; rw_[1] += rw_[3]; rw_[2] = 0.0f; rw_[3] = 0.0f;
            } else if (ri_[2] == ri_[1]) {
                rw_[1] += rw_[2]; rw_[2] = 0.0f;
            }
        }
        int ci_[4]; float cw_[4];
        {
            const float Xa = x1 + ((float)pw + 0.25f) * bin_w;
            const float Xb = x1 + ((float)pw + 0.75f) * bin_w;
            const float va = (Xa > -1.0f && Xa < (float)W_) ? 0.25f : 0.0f; // folds mean/4
            const float vb = (Xb > -1.0f && Xb < (float)W_) ? 0.25f : 0.0f;
            const float Xca = fminf(fmaxf(Xa, 0.0f), (float)(W_ - 1));
            const float Xcb = fminf(fmaxf(Xb, 0.0f), (float)(W_ - 1));
            const int x0a = (int)floorf(Xca);
            const int x0b = (int)floorf(Xcb);
            const float lxa = Xca - (float)x0a;
            const float lxb = Xcb - (float)x0b;
            ci_[0] = x0a; ci_[1] = min(x0a + 1, W_ - 1);
            ci_[2] = x0b; ci_[3] = min(x0b + 1, W_ - 1);
            cw_[0] = va * (1.0f - lxa); cw_[1] = va * lxa;
            cw_[2] = vb * (1.0f - lxb); cw_[3] = vb * lxb;
            if (ci_[1] == ci_[0]) { cw_[0] += cw_[1]; cw_[1] = 0.0f; }
            if (ci_[3] == ci_[2]) { cw_[2] += cw_[3]; cw_[3] = 0.0f; }
            if (ci_[2] == ci_[0]) {
                cw_[0] += cw_[2]; cw_[1] += cw_[3]; cw_[2] = 0.0f; cw_[3] = 0.0f;
            } else if (ci_[2] == ci_[1]) {
                cw_[1] += cw_[2]; cw_[2] = 0.0f;
            }
        }

        int   offs[16]; float wts[16];
#pragma unroll
        for (int r = 0; r < 4; ++r)
#pragma unroll
            for (int c = 0; c < 4; ++c) {
                offs[r * 4 + c] = (ri_[r] * W_ + ci_[c]) * (C_ / 4);
                wts[r * 4 + c]  = rw_[r] * cw_[c];
            }
        f4_t f[16];
#pragma unroll
        for (int k = 0; k < 16; ++k)
            if (wts[k] != 0.0f) f[k] = fbase[offs[k]];   // surviving loads batched
        f4_t acc = (f4_t){0.f, 0.f, 0.f, 0.f};
#pragma unroll
        for (int k = 0; k < 16; ++k)
            if (wts[k] != 0.0f) acc += wts[k] * f[k];

        const int c0 = lane * 4;   // [c][s] tile, stride 49 -> conflict-free
        lds[(c0 + 0) * 49 + s] = acc.x;
        lds[(c0 + 1) * 49 + s] = acc.y;
        lds[(c0 + 2) * 49 + s] = acc.z;
        lds[(c0 + 3) * 49 + s] = acc.w;
    }
}

// ---------------------------------------------------------------- obj pass
// 96 blocks: pool each object roi into ws_obj (regular stores -> cache-resident
// for the union pass's re-reads). Small rois, heavy dedup -> fast.
__global__ __launch_bounds__(256) void obj_kernel(
        const float* __restrict__ featT, const float* __restrict__ boxes,
        float* __restrict__ ws_obj) {
    __shared__ float lds[CHW_OUT];
    const int blk = blockIdx.x;             // 96 = 8*12: XCD swizzle preserved
    const int b   = (blk & 7) >> 1;
    const int m   = ((blk >> 3) << 1) | (blk & 1);

    const float* bp = boxes + ((size_t)b * N_OBJ + m) * 4;
    const int lane = threadIdx.x & 63;
    const int wv   = threadIdx.x >> 6;
    const f4_t* fbase = (const f4_t*)(featT + (size_t)b * HW_ * C_) + lane;
    pool_to_lds(fbase, bp[0], bp[1], bp[2], bp[3], lds, lane, wv);
    __syncthreads();

    const f4_t* s4 = (const f4_t*)lds;
    f4_t* d4 = (f4_t*)(ws_obj + ((size_t)b * N_OBJ + m) * CHW_OUT);
    for (int idx = threadIdx.x; idx < CHW_OUT / 4; idx += 256)
        d4[idx] = s4[idx];
}

// ---------------------------------------------------------------- union pass
// 1104 blocks, one per pair. Pool the union roi, then write ALL THREE slots:
// slot0 = ws_obj[i], slot1 = ws_obj[j] (cached reads), slot2 = LDS. The three
// slots are contiguous -> one 147 KB nontemporal burst per block, write load
// perfectly balanced across the grid (fixes R1's 96-block fan-out tail).
__global__ __launch_bounds__(256) void union_kernel(
        const float* __restrict__ featT, const float* __restrict__ boxes,
        const float* __restrict__ ws_obj, float* __restrict__ out) {
    __shared__ float lds[CHW_OUT];
    const int blk = blockIdx.x;             // 1104 = 8*138: swizzle preserved
    const int b   = (blk & 7) >> 1;
    const int p   = ((blk >> 3) << 1) | (blk & 1);

    int ii = 0, rem = p;
    while (rem >= N_OBJ - 1 - ii) { rem -= (N_OBJ - 1 - ii); ++ii; }
    const int jj = ii + 1 + rem;
    const float* b1 = boxes + ((size_t)b * N_OBJ + ii) * 4;
    const float* b2 = boxes + ((size_t)b * N_OBJ + jj) * 4;
    const float x1 = fminf(b1[0], b2[0]), y1 = fminf(b1[1], b2[1]);
    const float x2 = fmaxf(b1[2], b2[2]), y2 = fmaxf(b1[3], b2[3]);

    const int lane = threadIdx.x & 63;
    const int wv   = threadIdx.x >> 6;
    const f4_t* fbase = (const f4_t*)(featT + (size_t)b * HW_ * C_) + lane;
    pool_to_lds(fbase, x1, y1, x2, y2, lds, lane, wv);
    __syncthreads();

    const f4_t* s4 = (const f4_t*)lds;
    const f4_t* si = (const f4_t*)(ws_obj + ((size_t)b * N_OBJ + ii) * CHW_OUT);
    const f4_t* sj = (const f4_t*)(ws_obj + ((size_t)b * N_OBJ + jj) * CHW_OUT);
    f4_t* d4 = (f4_t*)(out + ((size_t)(b * P_ + p)) * 3 * CHW_OUT);
    for (int idx = threadIdx.x; idx < CHW_OUT / 4; idx += 256) {
        const f4_t v0 = si[idx];
        const f4_t v1 = sj[idx];
        const f4_t v2 = s4[idx];
        __builtin_nontemporal_store(v0, d4 + idx);
        __builtin_nontemporal_store(v1, d4 + (CHW_OUT / 4) + idx);
        __builtin_nontemporal_store(v2, d4 + 2 * (CHW_OUT / 4) + idx);
    }
}

extern "C" void kernel_launch(void* const* d_in, const int* in_sizes, int n_in,
                              void* d_out, int out_size, void* d_ws, size_t ws_size,
                              hipStream_t stream) {
    const float* feat  = (const float*)d_in[0];   // [B,C,H,W] fp32
    const float* boxes = (const float*)d_in[1];   // [B,N,4]  fp32
    float* out = (float*)d_out;                   // [B*P,3,C,7,7] fp32

    float* featT  = (float*)d_ws;                          // 40.96 MB
    float* ws_obj = featT + (size_t)B_ * HW_ * C_;         // 4.82 MB

    transpose_kernel<<<dim3((HW_ + 63) / 64, C_ / 64, B_), 256, 0, stream>>>(feat, featT);
    obj_kernel<<<B_ * N_OBJ, 256, 0, stream>>>(featT, boxes, ws_obj);
    union_kernel<<<B_ * P_, 256, 0, stream>>>(featT, boxes, ws_obj, out);
}

// Round 3
// 266.783 us; speedup vs baseline: 1.0096x; 1.0096x over previous
//
#include <hip/hip_runtime.h>

#define B_    4
#define N_OBJ 24
#define C_    256
#define H_    100
#define W_    100
#define HW_   (H_ * W_)
#define OUT_  7
#define P_    276              // N*(N-1)/2
#define M_    (N_OBJ + P_)     // 300 rois per batch
#define SCALE_ 0.25f
#define CHW_OUT (C_ * OUT_ * OUT_)   // 12544 floats per roi-slot chunk

typedef float f4_t __attribute__((ext_vector_type(4)));
typedef _Float16 h2_t __attribute__((ext_vector_type(2)));
typedef _Float16 h4_t __attribute__((ext_vector_type(4)));

// ---------------------------------------------------------------- transpose
// feat [B,C,H,W] fp32 -> featT [B,H*W,C] fp16.
// fp16 halves gather bytes AND shrinks per-batch featT to 5.1 MB -> fits the
// batch's 2x4MB L2s (the R0-R2 fp32 featT was 10.2 MB/batch -> L2 thrash).
__global__ __launch_bounds__(256) void transpose_kernel(
        const float* __restrict__ feat, _Float16* __restrict__ featT) {
    __shared__ float tile[64][65];
    const int b   = blockIdx.z;
    const int c0  = blockIdx.y * 64;
    const int px0 = blockIdx.x * 64;
    const int t   = threadIdx.x;
    const int cl  = t >> 6;   // 0..3
    const int px  = t & 63;
#pragma unroll
    for (int k = 0; k < 16; ++k) {
        const int c_loc = cl + k * 4;
        const int gpx   = px0 + px;
        tile[c_loc][px] = (gpx < HW_)
            ? feat[((size_t)b * C_ + c0 + c_loc) * HW_ + gpx] : 0.0f;
    }
    __syncthreads();
    // writer: each lane emits a half2 (2 consecutive channels) for 8 px rows
    const int c2 = (t & 31) << 1;   // 0,2,..,62
    const int pl = t >> 5;          // 0..7
#pragma unroll
    for (int k = 0; k < 8; ++k) {
        const int px_l = pl + k * 8;
        const int gpx  = px0 + px_l;
        if (gpx < HW_) {
            h2_t v;
            v.x = (_Float16)tile[c2][px_l];       // tile bank stride 2 -> 2-way (free)
            v.y = (_Float16)tile[c2 + 1][px_l];
            *(h2_t*)(featT + ((size_t)b * HW_ + gpx) * C_ + c0 + c2) = v;
        }
    }
}

// ---------------------------------------------------------------- fused roi
// R1 structure (best measured: 248.5 µs) with fp16 featT gathers.
// One block per roi; lane covers 4 channels (8 B fp16 loads); wave covers a
// bin. Exact row/col dedup via rank-1 weight structure; zero-weight loads
// skipped (wave-uniform branches). Obj blocks (blockIdx 0..95, start first)
// fan their tile out to the 23 pair slots directly from LDS.
// XCD swizzle: batch b -> XCDs {2b,2b+1} so featT stays L2-resident.
__global__ __launch_bounds__(256) void roi_fused_kernel(
        const _Float16* __restrict__ featT,   // [B, HW, C] fp16
        const float* __restrict__ boxes,      // [B, N, 4]
        float* __restrict__ out) {            // [B*P, 3, C, 49]
    __shared__ float lds[CHW_OUT];            // 49 KiB -> 3 blocks/CU
    const int blk    = blockIdx.x;
    const bool is_obj = blk < B_ * N_OBJ;
    int b, m;
    if (is_obj) {
        b = (blk & 7) >> 1;                               // batch 0..3
        m = ((blk >> 3) << 1) | (blk & 1);                // obj 0..23
    } else {
        const int t = blk - B_ * N_OBJ;                   // 96 % 8 == 0: swizzle kept
        b = (t & 7) >> 1;
        m = N_OBJ + (((t >> 3) << 1) | (t & 1));          // union 24..299
    }

    float x1, y1, x2, y2;
    if (is_obj) {
        const float* bp = boxes + ((size_t)b * N_OBJ + m) * 4;
        x1 = bp[0]; y1 = bp[1]; x2 = bp[2]; y2 = bp[3];
    } else {
        int p = m - N_OBJ;
        int ii = 0, rem = p;
        while (rem >= N_OBJ - 1 - ii) { rem -= (N_OBJ - 1 - ii); ++ii; }
        const int jj = ii + 1 + rem;
        const float* b1 = boxes + ((size_t)b * N_OBJ + ii) * 4;
        const float* b2 = boxes + ((size_t)b * N_OBJ + jj) * 4;
        x1 = fminf(b1[0], b2[0]); y1 = fminf(b1[1], b2[1]);
        x2 = fmaxf(b1[2], b2[2]); y2 = fmaxf(b1[3], b2[3]);
    }
    x1 *= SCALE_; y1 *= SCALE_; x2 *= SCALE_; y2 *= SCALE_;
    const float bin_w = fmaxf(x2 - x1, 1.0f) * (1.0f / OUT_);
    const float bin_h = fmaxf(y2 - y1, 1.0f) * (1.0f / OUT_);

    const int lane = threadIdx.x & 63;
    const int wv   = threadIdx.x >> 6;   // 0..3
    const h4_t* fbase = (const h4_t*)(featT + (size_t)b * HW_ * C_) + lane;

    for (int s = wv; s < OUT_ * OUT_; s += 4) {
        const int ph = s / OUT_, pw = s - ph * OUT_;

        // ---- rows: 2 samples x 2 corners, merged exactly on index collision
        int ri_[4]; float rw_[4];
        {
            const float Ya = y1 + ((float)ph + 0.25f) * bin_h;
            const float Yb = y1 + ((float)ph + 0.75f) * bin_h;
            const float va = (Ya > -1.0f && Ya < (float)H_) ? 1.0f : 0.0f;
            const float vb = (Yb > -1.0f && Yb < (float)H_) ? 1.0f : 0.0f;
            const float Yca = fminf(fmaxf(Ya, 0.0f), (float)(H_ - 1));
            const float Ycb = fminf(fmaxf(Yb, 0.0f), (float)(H_ - 1));
            const int y0a = (int)floorf(Yca);
            const int y0b = (int)floorf(Ycb);
            const float lya = Yca - (float)y0a;
            const float lyb = Ycb - (float)y0b;
            ri_[0] = y0a; ri_[1] = min(y0a + 1, H_ - 1);
            ri_[2] = y0b; ri_[3] = min(y0b + 1, H_ - 1);
            rw_[0] = va * (1.0f - lya); rw_[1] = va * lya;
            rw_[2] = vb * (1.0f - lyb); rw_[3] = vb * lyb;
            if (ri_[1] == ri_[0]) { rw_[0] += rw_[1]; rw_[1] = 0.0f; }
            if (ri_[3] == ri_[2]) { rw_[2] += rw_[3]; rw_[3] = 0.0f; }
            if (ri_[2] == ri_[0]) {
                rw_[0] += rw_[2]; rw_[1] += rw_[3]; rw_[2] = 0.0f; rw_[3] = 0.0f;
            } else if (ri_[2] == ri_[1]) {
                rw_[1] += rw_[2]; rw_[2] = 0.0f;
            }
        }
        // ---- cols: same, /4 sample-mean folded into the weights
        int ci_[4]; float cw_[4];
        {
            const float Xa = x1 + ((float)pw + 0.25f) * bin_w;
            const float Xb = x1 + ((float)pw + 0.75f) * bin_w;
            const float va = (Xa > -1.0f && Xa < (float)W_) ? 0.25f : 0.0f;
            const float vb = (Xb > -1.0f && Xb < (float)W_) ? 0.25f : 0.0f;
            const float Xca = fminf(fmaxf(Xa, 0.0f), (float)(W_ - 1));
            const float Xcb = fminf(fmaxf(Xb, 0.0f), (float)(W_ - 1));
            const int x0a = (int)floorf(Xca);
            const int x0b = (int)floorf(Xcb);
            const float lxa = Xca - (float)x0a;
            const float lxb = Xcb - (float)x0b;
            ci_[0] = x0a; ci_[1] = min(x0a + 1, W_ - 1);
            ci_[2] = x0b; ci_[3] = min(x0b + 1, W_ - 1);
            cw_[0] = va * (1.0f - lxa); cw_[1] = va * lxa;
            cw_[2] = vb * (1.0f - lxb); cw_[3] = vb * lxb;
            if (ci_[1] == ci_[0]) { cw_[0] += cw_[1]; cw_[1] = 0.0f; }
            if (ci_[3] == ci_[2]) { cw_[2] += cw_[3]; cw_[3] = 0.0f; }
            if (ci_[2] == ci_[0]) {
                cw_[0] += cw_[2]; cw_[1] += cw_[3]; cw_[2] = 0.0f; cw_[3] = 0.0f;
            } else if (ci_[2] == ci_[1]) {
                cw_[1] += cw_[2]; cw_[2] = 0.0f;
            }
        }

        int   offs[16]; float wts[16];
#pragma unroll
        for (int r = 0; r < 4; ++r)
#pragma unroll
            for (int c = 0; c < 4; ++c) {
                offs[r * 4 + c] = (ri_[r] * W_ + ci_[c]) * (C_ / 4);
                wts[r * 4 + c]  = rw_[r] * cw_[c];
            }
        h4_t f[16];
#pragma unroll
        for (int k = 0; k < 16; ++k)
            if (wts[k] != 0.0f) f[k] = fbase[offs[k]];   // surviving 8B loads batched
        f4_t acc = (f4_t){0.f, 0.f, 0.f, 0.f};
#pragma unroll
        for (int k = 0; k < 16; ++k)
            if (wts[k] != 0.0f) {
                acc.x += wts[k] * (float)f[k].x;
                acc.y += wts[k] * (float)f[k].y;
                acc.z += wts[k] * (float)f[k].z;
                acc.w += wts[k] * (float)f[k].w;
            }

        const int c0 = lane * 4;   // [c][s] tile, stride 49 -> conflict-free
        lds[(c0 + 0) * 49 + s] = acc.x;
        lds[(c0 + 1) * 49 + s] = acc.y;
        lds[(c0 + 2) * 49 + s] = acc.z;
        lds[(c0 + 3) * 49 + s] = acc.w;
    }
    __syncthreads();

    const f4_t* s4 = (const f4_t*)lds;
    if (!is_obj) {
        const int p = m - N_OBJ;
        f4_t* d4 = (f4_t*)(out + (((size_t)(b * P_ + p)) * 3 + 2) * CHW_OUT);
        for (int idx = threadIdx.x; idx < CHW_OUT / 4; idx += 256)
            __builtin_nontemporal_store(s4[idx], d4 + idx);  // don't evict featT
    } else {
        // object roi m -> slot 0 of pairs (m,q>m), slot 1 of pairs (q<m,m)
        for (int q = 0; q < N_OBJ; ++q) {
            if (q == m) continue;
            const int i = min(m, q), j = max(m, q);
            const int p = i * (2 * N_OBJ - i - 1) / 2 + (j - i - 1);
            const int slot = (m < q) ? 0 : 1;
            f4_t* d4 = (f4_t*)(out + (((size_t)(b * P_ + p)) * 3 + slot) * CHW_OUT);
            for (int idx = threadIdx.x; idx < CHW_OUT / 4; idx += 256)
                __builtin_nontemporal_store(s4[idx], d4 + idx);
        }
    }
}

extern "C" void kernel_launch(void* const* d_in, const int* in_sizes, int n_in,
                              void* d_out, int out_size, void* d_ws, size_t ws_size,
                              hipStream_t stream) {
    const float* feat  = (const float*)d_in[0];   // [B,C,H,W] fp32
    const float* boxes = (const float*)d_in[1];   // [B,N,4]  fp32
    float* out = (float*)d_out;                   // [B*P,3,C,7,7] fp32

    _Float16* featT = (_Float16*)d_ws;            // 20.48 MB fp16

    transpose_kernel<<<dim3((HW_ + 63) / 64, C_ / 64, B_), 256, 0, stream>>>(feat, featT);
    roi_fused_kernel<<<B_ * M_, 256, 0, stream>>>(featT, boxes, out);
}

// Round 6
// 242.904 us; speedup vs baseline: 1.1089x; 1.0983x over previous
//
#include <hip/hip_runtime.h>

#define B_    4
#define N_OBJ 24
#define C_    256
#define H_    100
#define W_    100
#define HW_   (H_ * W_)
#define OUT_  7
#define P_    276              // N*(N-1)/2
#define M_    (N_OBJ + P_)     // 300 rois per batch
#define SCALE_ 0.25f
#define CHW_OUT (C_ * OUT_ * OUT_)   // 12544 floats per roi-slot chunk

typedef float f4_t __attribute__((ext_vector_type(4)));
typedef int   i4_t __attribute__((ext_vector_type(4)));

// ---------------------------------------------------------------- transpose
// feat [B,C,H,W] -> featT [B,H*W,C]  fp32 (R1 version — near-roofline)
__global__ __launch_bounds__(256) void transpose_kernel(
        const float* __restrict__ feat, float* __restrict__ featT) {
    __shared__ float tile[64][65];
    const int b   = blockIdx.z;
    const int c0  = blockIdx.y * 64;
    const int px0 = blockIdx.x * 64;
    const int t   = threadIdx.x;
    const int cl  = t >> 6;   // 0..3
    const int px  = t & 63;
#pragma unroll
    for (int k = 0; k < 16; ++k) {
        const int c_loc = cl + k * 4;
        const int gpx   = px0 + px;
        tile[c_loc][px] = (gpx < HW_)
            ? feat[((size_t)b * C_ + c0 + c_loc) * HW_ + gpx] : 0.0f;
    }
    __syncthreads();
    const int c2 = t & 63;
    const int pl = t >> 6;
#pragma unroll
    for (int k = 0; k < 16; ++k) {
        const int px_l = pl + k * 4;
        const int gpx  = px0 + px_l;
        if (gpx < HW_)
            featT[((size_t)b * HW_ + gpx) * C_ + c0 + c2] = tile[c2][px_l];
    }
}

// ---------------------------------------------------------------- fused roi
// R1 structure (best measured: 248.5 µs) + separable weight precompute.
// Row weights depend only on ph (7 sets), col weights only on pw (7 sets):
// threads 0..13 compute them once per block into LDS; the bin loop reads
// them back as float4/int4 broadcasts + 16 mul + 16 add.
__global__ __launch_bounds__(256) void roi_fused_kernel(
        const float* __restrict__ featT,   // [B, HW, C]
        const float* __restrict__ boxes,   // [B, N, 4]
        float* __restrict__ out) {         // [B*P, 3, C, 49]
    __shared__ float lds[CHW_OUT];         // 49 KiB tile -> 3 blocks/CU
    __shared__ f4_t rww[OUT_], cww[OUT_];  // row/col weights (merged, dedup'd)
    __shared__ i4_t rof[OUT_], cof[OUT_];  // row/col offsets in f4 units

    const int blk    = blockIdx.x;
    const bool is_obj = blk < B_ * N_OBJ;
    int b, m;
    if (is_obj) {
        b = (blk & 7) >> 1;                               // batch 0..3
        m = ((blk >> 3) << 1) | (blk & 1);                // obj 0..23
    } else {
        const int t = blk - B_ * N_OBJ;                   // 96 % 8 == 0: swizzle kept
        b = (t & 7) >> 1;
        m = N_OBJ + (((t >> 3) << 1) | (t & 1));          // union 24..299
    }

    float x1, y1, x2, y2;
    if (is_obj) {
        const float* bp = boxes + ((size_t)b * N_OBJ + m) * 4;
        x1 = bp[0]; y1 = bp[1]; x2 = bp[2]; y2 = bp[3];
    } else {
        int p = m - N_OBJ;
        int ii = 0, rem = p;
        while (rem >= N_OBJ - 1 - ii) { rem -= (N_OBJ - 1 - ii); ++ii; }
        const int jj = ii + 1 + rem;
        const float* b1 = boxes + ((size_t)b * N_OBJ + ii) * 4;
        const float* b2 = boxes + ((size_t)b * N_OBJ + jj) * 4;
        x1 = fminf(b1[0], b2[0]); y1 = fminf(b1[1], b2[1]);
        x2 = fmaxf(b1[2], b2[2]); y2 = fmaxf(b1[3], b2[3]);
    }
    x1 *= SCALE_; y1 *= SCALE_; x2 *= SCALE_; y2 *= SCALE_;
    const float bin_w = fmaxf(x2 - x1, 1.0f) * (1.0f / OUT_);
    const float bin_h = fmaxf(y2 - y1, 1.0f) * (1.0f / OUT_);

    // ---- one-time separable weight precompute (threads 0..13) ----
    if (threadIdx.x < 2 * OUT_) {
        const bool isrow = threadIdx.x < OUT_;
        const int  ph    = isrow ? threadIdx.x : threadIdx.x - OUT_;
        const float org  = isrow ? y1 : x1;
        const float bs   = isrow ? bin_h : bin_w;
        const float vsc  = isrow ? 1.0f : 0.25f;          // fold sample-mean /4
        const int   mult = isrow ? W_ * (C_ / 4) : (C_ / 4);

        const float A  = org + ((float)ph + 0.25f) * bs;
        const float Bv = org + ((float)ph + 0.75f) * bs;
        const float va = (A  > -1.0f && A  < 100.0f) ? vsc : 0.0f;  // H_==W_==100
        const float vb = (Bv > -1.0f && Bv < 100.0f) ? vsc : 0.0f;
        const float Ac = fminf(fmaxf(A,  0.0f), 99.0f);
        const float Bc = fminf(fmaxf(Bv, 0.0f), 99.0f);
        const int  i0a = (int)floorf(Ac);
        const int  i0b = (int)floorf(Bc);
        const float la = Ac - (float)i0a;
        const float lb = Bc - (float)i0b;
        int   id[4] = { i0a, min(i0a + 1, 99), i0b, min(i0b + 1, 99) };
        float wt[4] = { va * (1.0f - la), va * la, vb * (1.0f - lb), vb * lb };
        if (id[1] == id[0]) { wt[0] += wt[1]; wt[1] = 0.0f; }   // edge clamp
        if (id[3] == id[2]) { wt[2] += wt[3]; wt[3] = 0.0f; }
        if (id[2] == id[0]) {                                    // same cell
            wt[0] += wt[2]; wt[1] += wt[3]; wt[2] = 0.0f; wt[3] = 0.0f;
        } else if (id[2] == id[1]) {                             // adjacent cell
            wt[1] += wt[2]; wt[2] = 0.0f;
        }
        const f4_t wv4 = (f4_t){wt[0], wt[1], wt[2], wt[3]};
        const i4_t ov4 = (i4_t){id[0] * mult, id[1] * mult, id[2] * mult, id[3] * mult};
        if (isrow) { rww[ph] = wv4; rof[ph] = ov4; }
        else       { cww[ph] = wv4; cof[ph] = ov4; }
    }
    __syncthreads();

    const int lane = threadIdx.x & 63;
    const int wv   = threadIdx.x >> 6;   // 0..3
    const f4_t* fbase = (const f4_t*)(featT + (size_t)b * HW_ * C_) + lane;

    for (int s = wv; s < OUT_ * OUT_; s += 4) {
        const int ph = (s * 37) >> 8;    // exact s/7 for s in [0,49)
        const int pw = s - ph * OUT_;

        const f4_t rw = rww[ph];         // broadcast LDS reads
        const i4_t ro = rof[ph];
        const f4_t cw = cww[pw];
        const i4_t co = cof[pw];

        int   offs[16]; float wts[16];
#pragma unroll
        for (int r = 0; r < 4; ++r)
#pragma unroll
            for (int c = 0; c < 4; ++c) {
                offs[r * 4 + c] = ro[r] + co[c];
                wts[r * 4 + c]  = rw[r] * cw[c];
            }
        f4_t f[16];
#pragma unroll
        for (int k = 0; k < 16; ++k)
            if (wts[k] != 0.0f) f[k] = fbase[offs[k]];   // surviving loads batched
        f4_t acc = (f4_t){0.f, 0.f, 0.f, 0.f};
#pragma unroll
        for (int k = 0; k < 16; ++k)
            if (wts[k] != 0.0f) acc += wts[k] * f[k];

        const int c0 = lane * 4;   // [c][s] tile, stride 49 -> conflict-free
        lds[(c0 + 0) * 49 + s] = acc.x;
        lds[(c0 + 1) * 49 + s] = acc.y;
        lds[(c0 + 2) * 49 + s] = acc.z;
        lds[(c0 + 3) * 49 + s] = acc.w;
    }
    __syncthreads();

    const f4_t* s4 = (const f4_t*)lds;
    if (!is_obj) {
        const int p = m - N_OBJ;
        f4_t* d4 = (f4_t*)(out + (((size_t)(b * P_ + p)) * 3 + 2) * CHW_OUT);
        for (int idx = threadIdx.x; idx < CHW_OUT / 4; idx += 256)
            __builtin_nontemporal_store(s4[idx], d4 + idx);  // don't evict featT
    } else {
        // object roi m -> slot 0 of pairs (m,q>m), slot 1 of pairs (q<m,m)
        for (int q = 0; q < N_OBJ; ++q) {
            if (q == m) continue;
            const int i = min(m, q), j = max(m, q);
            const int p = i * (2 * N_OBJ - i - 1) / 2 + (j - i - 1);
            const int slot = (m < q) ? 0 : 1;
            f4_t* d4 = (f4_t*)(out + (((size_t)(b * P_ + p)) * 3 + slot) * CHW_OUT);
            for (int idx = threadIdx.x; idx < CHW_OUT / 4; idx += 256)
                __builtin_nontemporal_store(s4[idx], d4 + idx);
        }
    }
}

extern "C" void kernel_launch(void* const* d_in, const int* in_sizes, int n_in,
                              void* d_out, int out_size, void* d_ws, size_t ws_size,
                              hipStream_t stream) {
    const float* feat  = (const float*)d_in[0];   // [B,C,H,W] fp32
    const float* boxes = (const float*)d_in[1];   // [B,N,4]  fp32
    float* out = (float*)d_out;                   // [B*P,3,C,7,7] fp32

    float* featT = (float*)d_ws;                  // 40.96 MB

    transpose_kernel<<<dim3((HW_ + 63) / 64, C_ / 64, B_), 256, 0, stream>>>(feat, featT);
    roi_fused_kernel<<<B_ * M_, 256, 0, stream>>>(featT, boxes, out);
}